// Round 5
// baseline (1208.345 us; speedup 1.0000x reference)
//
#include <hip/hip_runtime.h>
#include <hip/hip_bf16.h>
#include <cstdint>
#include <cstddef>

#define B_  256
#define Z_  512
#define H_  2048
#define T_  16
#define H3_ 6144
#define NWG 256

using short8 = __attribute__((ext_vector_type(8))) short;
using bf16x8 = __attribute__((ext_vector_type(8))) __bf16;
using f32x4  = __attribute__((ext_vector_type(4))) float;

__device__ __forceinline__ f32x4 mfma_bf16(short8 a, short8 b, f32x4 c) {
  return __builtin_amdgcn_mfma_f32_16x16x32_bf16(
      __builtin_bit_cast(bf16x8, a), __builtin_bit_cast(bf16x8, b), c, 0, 0, 0);
}

__device__ __forceinline__ unsigned short f2bf(float f) {
  unsigned int u = __builtin_bit_cast(unsigned int, f);
  u = (u + 0x7FFFu + ((u >> 16) & 1u)) >> 16;
  return (unsigned short)u;
}

__device__ __forceinline__ float sigmoidf_(float x) { return 1.0f / (1.0f + __expf(-x)); }

// LDS XOR swizzle: tiles are [rows][64] bf16 (128 B rows = 8x16B chunks).
__device__ __forceinline__ int swz(int row, int chunk) {
  return row * 64 + ((chunk ^ (row & 7)) << 3);   // ushort element offset
}

// Grid barrier, NO acquire-invalidate. Correctness contract: all cross-WG
// buffers are write-once per dispatch and first-touched by readers only
// after the barrier (kernel-start dispatch-acquire invalidated all L2s).
// Release-wb pushes dirty lines to LLC; readers first-touch-miss to LLC.
__device__ __forceinline__ void gbar(int* cnt, int* sense, int& ls) {
  __syncthreads();
  if (threadIdx.x == 0) {
    ls ^= 1;
    __builtin_amdgcn_fence(__ATOMIC_RELEASE, "agent");   // wb dirty L2 -> LLC
    if (__hip_atomic_fetch_add(cnt, 1, __ATOMIC_RELAXED, __HIP_MEMORY_SCOPE_AGENT) == NWG - 1) {
      __hip_atomic_store(cnt, 0, __ATOMIC_RELAXED, __HIP_MEMORY_SCOPE_AGENT);
      __hip_atomic_store(sense, ls, __ATOMIC_RELAXED, __HIP_MEMORY_SCOPE_AGENT);
    } else {
      while (__hip_atomic_load(sense, __ATOMIC_RELAXED, __HIP_MEMORY_SCOPE_AGENT) != ls)
        __builtin_amdgcn_s_sleep(4);
    }
  }
  __syncthreads();
}

// ---------------------------------------------------------------------------
// 64x64 GEMM tile, 512 threads (8 waves = 2 m-halves x 4 col-16s).
// C = A@B^T (+add)(+bias). smem: sA 8KB, sB 8KB.
// ---------------------------------------------------------------------------
__device__ __forceinline__ void dev_gemm64(
    unsigned short* sA, unsigned short* sB,
    const unsigned short* __restrict__ A,
    const unsigned short* __restrict__ Bw, int K,
    const float* __restrict__ addsrc, int add_ld,
    const float* __restrict__ bias,
    unsigned short* __restrict__ out_bf,
    float* __restrict__ out_f, int ldo, int mi, int ni)
{
  const int tid = threadIdx.x;
  const int m0 = mi * 64, n0 = ni * 64;
  const int wave = tid >> 6, lane = tid & 63;
  const int wr = wave & 1, wc = wave >> 1;
  const int q = lane >> 4, c16 = lane & 15;
  const int lr = tid >> 3, lc8 = tid & 7;
  f32x4 acc[2] = {};
  const size_t aoff = (size_t)(m0 + lr) * K;
  const size_t boff = (size_t)(n0 + lr) * K;
  uint4 ra, rb;
  const int nIter = K >> 6;
  int gc = lc8 * 8;
  ra = *(const uint4*)(A  + aoff + gc);
  rb = *(const uint4*)(Bw + boff + gc);
  for (int it = 0; it < nIter; ++it) {
    __syncthreads();
    *(uint4*)(sA + swz(lr, lc8)) = ra;
    *(uint4*)(sB + swz(lr, lc8)) = rb;
    __syncthreads();
    if (it + 1 < nIter) {
      gc = ((it + 1) << 6) + lc8 * 8;
      ra = *(const uint4*)(A  + aoff + gc);
      rb = *(const uint4*)(Bw + boff + gc);
    }
#pragma unroll
    for (int kk = 0; kk < 2; ++kk) {
      short8 af0 = *(const short8*)(sA + swz(wr * 32 + c16,      kk * 4 + q));
      short8 af1 = *(const short8*)(sA + swz(wr * 32 + 16 + c16, kk * 4 + q));
      short8 bf  = *(const short8*)(sB + swz(wc * 16 + c16,      kk * 4 + q));
      acc[0] = mfma_bf16(af0, bf, acc[0]);
      acc[1] = mfma_bf16(af1, bf, acc[1]);
    }
  }
#pragma unroll
  for (int i = 0; i < 2; ++i)
#pragma unroll
    for (int v = 0; v < 4; ++v) {
      const int row = m0 + wr * 32 + i * 16 + q * 4 + v;
      const int col = n0 + wc * 16 + c16;
      float val = acc[i][v];
      if (addsrc) val += addsrc[(size_t)row * add_ld + col];
      if (bias)   val += bias[col];
      if (out_f)  out_f[(size_t)row * ldo + col] = val;
      if (out_bf) out_bf[(size_t)row * ldo + col] = f2bf(val);
    }
}

// ---------------------------------------------------------------------------
// GRU tile: 512 threads, 8 waves = (mh 2)x(cb 2)x(kk 2). kk-split removes
// B-fragment duplication (LDS 72KB/iter). Cross-wave kk-reduce at the end
// via conflict-free 32KB LDS buffer, then epilogue on kk==0 waves.
// M=64 rows x (4 gates x 32 cols). smem: sA 8KB + sW 16KB; red 32KB overlay.
// ---------------------------------------------------------------------------
__device__ __forceinline__ void dev_gru(
    unsigned char* SMEM,
    const unsigned short* __restrict__ A, int K,
    const unsigned short* __restrict__ Wr,
    const unsigned short* __restrict__ Wz,
    const unsigned short* __restrict__ Wn,
    const unsigned short* __restrict__ Whn,
    const float* __restrict__ cr, const float* __restrict__ cz,
    const float* __restrict__ cn, const float* __restrict__ chn,
    const float* __restrict__ ascale_ptr, float hn_scale,
    const float* __restrict__ h_old,
    float* __restrict__ h_new,
    unsigned short* __restrict__ h_hist,
    int m0, int n0)
{
  unsigned short* sA = (unsigned short*)SMEM;
  unsigned short* sW = (unsigned short*)(SMEM + 8192);
  const int tid = threadIdx.x;
  const int wave = tid >> 6, lane = tid & 63;
  const int kk = wave & 1, cb = (wave >> 1) & 1, mh = wave >> 2;
  const int q = lane >> 4, c16 = lane & 15;
  const int lr = tid >> 3, lc8 = tid & 7;
  f32x4 acc[2][4] = {};   // [row-block 16][gate]
  const size_t aoff = (size_t)(m0 + lr) * K;
  const size_t woff = (size_t)(n0 + (lr & 31)) * K;
  const int glo = lr >> 5;  // staging rows 0-31 -> gates 0/2, 32-63 -> 1/3
  const unsigned short* Wlo = glo ? Wz  : Wr;
  const unsigned short* Whi = glo ? Whn : Wn;
  const int dlo = (glo ? 2048 : 0)    + swz(lr & 31, lc8);
  const int dhi = (glo ? 6144 : 4096) + swz(lr & 31, lc8);
  const int da  = swz(lr, lc8);
  uint4 ra[2], rlo[2], rhi[2];
  const int nIter = K >> 6;
  {
    int gc = lc8 * 8;
    ra[0]  = *(const uint4*)(A   + aoff + gc);
    rlo[0] = *(const uint4*)(Wlo + woff + gc);
    rhi[0] = *(const uint4*)(Whi + woff + gc);
    gc += 64;
    ra[1]  = *(const uint4*)(A   + aoff + gc);
    rlo[1] = *(const uint4*)(Wlo + woff + gc);
    rhi[1] = *(const uint4*)(Whi + woff + gc);
  }
  for (int it = 0; it < nIter; ++it) {
    const int s = it & 1;
    __syncthreads();
    *(uint4*)(sA + da)  = ra[s];
    *(uint4*)(sW + dlo) = rlo[s];
    *(uint4*)(sW + dhi) = rhi[s];
    __syncthreads();
    if (it + 2 < nIter) {
      const int gc = ((it + 2) << 6) + lc8 * 8;
      ra[s]  = *(const uint4*)(A   + aoff + gc);
      rlo[s] = *(const uint4*)(Wlo + woff + gc);
      rhi[s] = *(const uint4*)(Whi + woff + gc);
    }
    // each wave consumes only its kk window (k = it*64 + kk*32 .. +31)
    short8 af0 = *(const short8*)(sA + swz(mh * 32 + c16,      kk * 4 + q));
    short8 af1 = *(const short8*)(sA + swz(mh * 32 + 16 + c16, kk * 4 + q));
#pragma unroll
    for (int g = 0; g < 4; ++g) {
      short8 bf = *(const short8*)(sW + g * 2048 + swz(cb * 16 + c16, kk * 4 + q));
      acc[0][g] = mfma_bf16(af0, bf, acc[0][g]);
      acc[1][g] = mfma_bf16(af1, bf, acc[1][g]);
    }
  }
  // ---- cross-wave kk reduction (conflict-free: consecutive lanes -> consecutive f32)
  __syncthreads();
  float* red = (float*)SMEM;               // 4 wp x 8 slots x 4 comps x 64 lanes = 32KB
  const int wp = mh * 2 + cb;
  if (kk == 1) {
#pragma unroll
    for (int rb = 0; rb < 2; ++rb)
#pragma unroll
      for (int g = 0; g < 4; ++g)
#pragma unroll
        for (int c = 0; c < 4; ++c)
          red[(((wp * 8 + rb * 4 + g) << 2) + c) * 64 + lane] = acc[rb][g][c];
  }
  __syncthreads();
  if (kk == 0) {
#pragma unroll
    for (int rb = 0; rb < 2; ++rb)
#pragma unroll
      for (int g = 0; g < 4; ++g)
#pragma unroll
        for (int c = 0; c < 4; ++c)
          acc[rb][g][c] += red[(((wp * 8 + rb * 4 + g) << 2) + c) * 64 + lane];
    const float as = ascale_ptr ? ascale_ptr[0] : 1.0f;
#pragma unroll
    for (int rb = 0; rb < 2; ++rb)
#pragma unroll
      for (int v = 0; v < 4; ++v) {
        const int row = m0 + mh * 32 + rb * 16 + q * 4 + v;
        const int col = n0 + cb * 16 + c16;
        const float R   = sigmoidf_(as * acc[rb][0][v] + cr[col]);
        const float U   = sigmoidf_(as * acc[rb][1][v] + cz[col]);
        const float hnv = hn_scale * (as * acc[rb][3][v]) + chn[col];
        const float Nv  = tanhf(as * acc[rb][2][v] + cn[col] + R * hnv);
        const float ho  = h_old ? h_old[(size_t)row * H_ + col] : 0.0f;
        const float hv  = (1.0f - U) * Nv + U * ho;
        h_new[(size_t)row * H_ + col]  = hv;
        h_hist[(size_t)row * H_ + col] = f2bf(hv);
      }
  }
}

__global__ void initk(int* cnt, int* sense) {
  if (threadIdx.x == 0) { *cnt = 0; *sense = 0; }
}

// ---------------------------------------------------------------------------
// Persistent mega-kernel: 256 WGs x 512 threads, L2-retaining barriers.
// ---------------------------------------------------------------------------
__global__ __launch_bounds__(512, 1) void mega(
    const float* __restrict__ z, const float* __restrict__ fc_w,
    const float* __restrict__ fc_b, const float* __restrict__ fc_u,
    const float* __restrict__ w_ih, const float* __restrict__ w_hh,
    const float* __restrict__ b_ih, const float* __restrict__ b_hh,
    const float* __restrict__ lin_w, const float* __restrict__ lin_b,
    unsigned short* w_ih_q, unsigned short* w_hhn_q, unsigned short* lin_w_q,
    unsigned short* lin_wT_q, unsigned short* fc_w_q, unsigned short* z_q,
    unsigned short* x0_q, unsigned short* Wsum_r, unsigned short* Wsum_z,
    unsigned short* Wn_c, unsigned short* Hhist, float* h_f32,
    float* outs, float* c0r, float* c0z, float* c0n, float* c1r, float* c1z,
    float* c1n, float* chn, float* dvec, float* evec, float* sig_tmp,
    float* invsig, float* out, int* bar_cnt, int* bar_sense)
{
  __shared__ __align__(16) unsigned char SMEM[32768];
  unsigned short* sAg = (unsigned short*)SMEM;          // 8KB
  unsigned short* sWg = (unsigned short*)(SMEM + 8192); // 8KB (gemm B)
  const int bid = blockIdx.x, tid = threadIdx.x;
  int ls = 0;

  // ---------------- Phase A: quant + transpose + dots -----------------------
  {
    const int gtid = bid * 512 + tid;
    // float4 ranges: z 32768 | fc_w 65536 | w_ih 786432 | w_hhn 1048576 | lin_w 262144
    for (int i = gtid; i < 2195456; i += NWG * 512) {
      const float4* src; ushort4* dst; int idx;
      if (i < 32768)        { src = (const float4*)z;     dst = (ushort4*)z_q;     idx = i; }
      else if (i < 98304)   { src = (const float4*)fc_w;  dst = (ushort4*)fc_w_q;  idx = i - 32768; }
      else if (i < 884736)  { src = (const float4*)w_ih;  dst = (ushort4*)w_ih_q;  idx = i - 98304; }
      else if (i < 1933312) { src = (const float4*)(w_hh + (size_t)2 * H_ * H_);
                              dst = (ushort4*)w_hhn_q;    idx = i - 884736; }
      else                  { src = (const float4*)lin_w; dst = (ushort4*)lin_w_q; idx = i - 1933312; }
      float4 v = src[idx];
      ushort4 o; o.x = f2bf(v.x); o.y = f2bf(v.y); o.z = f2bf(v.z); o.w = f2bf(v.w);
      dst[idx] = o;
    }
    // transq: lin_w [512][2048] -> lin_wT_q [2048][512] bf16, 1024 tiles of 32x32
    float* tile = (float*)SMEM;  // [32][33]
    const int tx = tid & 31, ty = tid >> 5;   // ty in [0,16)
    for (int tt = bid; tt < 1024; tt += NWG) {
      const int bx = tt >> 4, by = tt & 15;
      const int k0 = bx * 32, z0 = by * 32;
      __syncthreads();
#pragma unroll
      for (int j = 0; j < 2; ++j)
        tile[(ty + j * 16) * 33 + tx] = lin_w[(size_t)(z0 + ty + j * 16) * H_ + k0 + tx];
      __syncthreads();
#pragma unroll
      for (int j = 0; j < 2; ++j)
        lin_wT_q[(size_t)(k0 + ty + j * 16) * Z_ + z0 + tx] = f2bf(tile[tx * 33 + ty + j * 16]);
    }
    // dots: dvec[row]=dot(w_ih[row],lin_b), evec[row]=dot(w_ih[row],fc_b)
    const int wave = tid >> 6, lane = tid & 63;
    for (int row = bid * 8 + wave; row < H3_; row += 2048) {
      float s1 = 0.f, s2 = 0.f;
      for (int c = lane; c < Z_; c += 64) {
        const float w = w_ih[(size_t)row * Z_ + c];
        s1 += w * lin_b[c]; s2 += w * fc_b[c];
      }
#pragma unroll
      for (int off = 32; off > 0; off >>= 1) {
        s1 += __shfl_down(s1, off); s2 += __shfl_down(s2, off);
      }
      if (lane == 0) { dvec[row] = s1; evec[row] = s2; }
    }
  }
  gbar(bar_cnt, bar_sense, ls);

  // ---- Phase B: WG0 sigma chain || {Wsum GEMMs, x0' GEMM, consts} ----------
  if (bid == 0) {
    float* red = (float*)SMEM;  // 512 floats
    float a = 0.f;
    for (int r = 0; r < Z_; ++r) a += fc_w[(size_t)r * Z_ + tid] * fc_u[r];
    sig_tmp[tid] = a;
    red[tid] = a * a;
    __syncthreads();
    for (int s = 256; s > 0; s >>= 1) { if (tid < s) red[tid] += red[tid + s]; __syncthreads(); }
    const float invn = 1.0f / (sqrtf(red[0]) + 1e-12f);
    __syncthreads();
    float b = 0.f;
    for (int c = 0; c < Z_; ++c) b += fc_w[(size_t)tid * Z_ + c] * sig_tmp[c];
    b *= invn;
    red[tid] = b * b;
    __syncthreads();
    for (int s = 256; s > 0; s >>= 1) { if (tid < s) red[tid] += red[tid + s]; __syncthreads(); }
    if (tid == 0) {
      const float s2 = red[0];
      invsig[0] = (sqrtf(s2) + 1e-12f) / s2;   // 1/sigma
    }
  } else {
    for (int j = bid - 1; j < 3108; j += NWG - 1) {
      if (j < 3072) {
        const int g = j >> 10, tt = j & 1023, mi = tt >> 5, ni = tt & 31;
        const float* adds = (g < 2) ? (w_hh + (size_t)g * H_ * H_) : nullptr;
        unsigned short* outw = (g == 0) ? Wsum_r : (g == 1) ? Wsum_z : Wn_c;
        dev_gemm64(sAg, sWg, w_ih_q + (size_t)g * H_ * Z_, lin_wT_q, Z_,
                   adds, H_, nullptr, outw, nullptr, H_, mi, ni);
      } else if (j < 3104) {
        const int tt = j - 3072, mi = tt >> 3, ni = tt & 7;  // x0' unscaled
        dev_gemm64(sAg, sWg, z_q, fc_w_q, Z_, nullptr, 0, nullptr,
                   x0_q, nullptr, Z_, mi, ni);
      } else {
        const int jj = (j - 3104) * 512 + tid;
        const float br = b_ih[jj], bz = b_ih[H_ + jj], bn = b_ih[2 * H_ + jj];
        const float hr = b_hh[jj], hz = b_hh[H_ + jj], hn = b_hh[2 * H_ + jj];
        c0r[jj] = br + hr + evec[jj];
        c0z[jj] = bz + hz + evec[H_ + jj];
        c0n[jj] = bn + evec[2 * H_ + jj];
        chn[jj] = hn;
        c1r[jj] = br + hr + dvec[jj];
        c1z[jj] = bz + hz + dvec[H_ + jj];
        c1n[jj] = bn + dvec[2 * H_ + jj];
      }
    }
  }
  gbar(bar_cnt, bar_sense, ls);

  // ---------------- Phase D: 16 GRU steps -----------------------------------
  {
    const int xcd = bid & 7, rest = bid >> 3;
    const int m_idx = rest & 3, grp = rest >> 2;
    const int n_idx = grp * 8 + xcd;
    const int m0 = m_idx * 64, n0 = n_idx * 32;
#pragma unroll 1
    for (int t = 0; t < T_; ++t) {
      const bool first = (t == 0);
      const unsigned short* Aq = first ? x0_q : (Hhist + (size_t)(t - 1) * B_ * H_);
      const int K = first ? Z_ : H_;
      const unsigned short* Wrp = first ? w_ih_q : Wsum_r;
      const unsigned short* Wzp = first ? (w_ih_q + (size_t)H_ * Z_) : Wsum_z;
      const unsigned short* Wnp = first ? (w_ih_q + (size_t)2 * H_ * Z_) : Wn_c;
      const unsigned short* Whp = first ? w_ih_q : w_hhn_q;  // dummy at t=0
      const float* pcr = first ? c0r : c1r;
      const float* pcz = first ? c0z : c1z;
      const float* pcn = first ? c0n : c1n;
      const float* asc = first ? invsig : nullptr;
      const float hscale = first ? 0.0f : 1.0f;
      const float* hold = first ? nullptr : (h_f32 + (size_t)((t - 1) & 1) * B_ * H_);
      float* hnew = h_f32 + (size_t)(t & 1) * B_ * H_;
      unsigned short* hh = Hhist + (size_t)t * B_ * H_;
      dev_gru(SMEM, Aq, K, Wrp, Wzp, Wnp, Whp, pcr, pcz, pcn, chn,
              asc, hscale, hold, hnew, hh, m0, n0);
      gbar(bar_cnt, bar_sense, ls);
    }
  }

  // ---------------- Phase E: outs = Hhist @ lin_w^T + lin_b -----------------
#pragma unroll 1
  for (int j = bid; j < 512; j += NWG) {
    const int mi = j >> 3, ni = j & 7;
    dev_gemm64(sAg, sWg, Hhist, lin_w_q, H_, nullptr, 0, lin_b,
               nullptr, outs, Z_, mi, ni);
  }
  gbar(bar_cnt, bar_sense, ls);

  // ---------------- Phase F: BN over batch + transpose ----------------------
  if (bid < 128) {
    float* s_sum  = (float*)SMEM;        // [8][64]
    float* s_sq   = s_sum + 512;         // [8][64]
    float* s_mean = s_sq + 512;          // [64]
    float* s_inv  = s_mean + 64;         // [64]
    const int t = bid >> 3, zb = bid & 7;
    const int zl = tid & 63, bp = tid >> 6;
    const int zc = zb * 64 + zl;
    float sum = 0.f, sq = 0.f;
    for (int b = bp * 32; b < bp * 32 + 32; ++b) {
      float v = outs[(size_t)(t * 256 + b) * Z_ + zc];
      sum += v; sq += v * v;
    }
    s_sum[bp * 64 + zl] = sum; s_sq[bp * 64 + zl] = sq;
    __syncthreads();
    if (bp == 0) {
      float S = 0.f, Q = 0.f;
#pragma unroll
      for (int p = 0; p < 8; ++p) { S += s_sum[p * 64 + zl]; Q += s_sq[p * 64 + zl]; }
      float mean = S * (1.0f / 256.0f);
      float var  = Q * (1.0f / 256.0f) - mean * mean;
      s_mean[zl] = mean;
      s_inv[zl]  = rsqrtf(var + 1e-5f);
    }
    __syncthreads();
    const float mean = s_mean[zl], inv = s_inv[zl];
    for (int b = bp * 32; b < bp * 32 + 32; ++b) {
      float v = outs[(size_t)(t * 256 + b) * Z_ + zc];
      out[(size_t)(b * T_ + t) * Z_ + zc] = (v - mean) * inv;
    }
  }
}

// ---------------------------------------------------------------------------
extern "C" void kernel_launch(void* const* d_in, const int* in_sizes, int n_in,
                              void* d_out, int out_size, void* d_ws, size_t ws_size,
                              hipStream_t stream) {
  const float* z     = (const float*)d_in[0];
  const float* fc_w  = (const float*)d_in[1];
  const float* fc_b  = (const float*)d_in[2];
  const float* fc_u  = (const float*)d_in[3];
  const float* w_ih  = (const float*)d_in[4];
  const float* w_hh  = (const float*)d_in[5];
  const float* b_ih  = (const float*)d_in[6];
  const float* b_hh  = (const float*)d_in[7];
  const float* lin_w = (const float*)d_in[8];
  const float* lin_b = (const float*)d_in[9];
  float* out = (float*)d_out;

  char* ws = (char*)d_ws;
  size_t off = 0;
  auto alloc = [&](size_t bytes) -> void* {
    off = (off + 255) & ~(size_t)255;
    void* p = ws + off;
    off += bytes;
    return p;
  };
  unsigned short* w_ih_q   = (unsigned short*)alloc((size_t)H3_ * Z_ * 2);
  unsigned short* w_hhn_q  = (unsigned short*)alloc((size_t)H_ * H_ * 2);
  unsigned short* lin_w_q  = (unsigned short*)alloc((size_t)Z_ * H_ * 2);
  unsigned short* lin_wT_q = (unsigned short*)alloc((size_t)Z_ * H_ * 2);
  unsigned short* fc_w_q   = (unsigned short*)alloc((size_t)Z_ * Z_ * 2);
  unsigned short* z_q      = (unsigned short*)alloc((size_t)B_ * Z_ * 2);
  unsigned short* x0_q     = (unsigned short*)alloc((size_t)B_ * Z_ * 2);
  unsigned short* Wsum_r   = (unsigned short*)alloc((size_t)H_ * H_ * 2);
  unsigned short* Wsum_z   = (unsigned short*)alloc((size_t)H_ * H_ * 2);
  unsigned short* Wn_c     = (unsigned short*)alloc((size_t)H_ * H_ * 2);
  unsigned short* Hhist    = (unsigned short*)alloc((size_t)T_ * B_ * H_ * 2);
  float* h_f32 = (float*)alloc((size_t)2 * B_ * H_ * 4);
  float* outs  = (float*)alloc((size_t)T_ * B_ * Z_ * 4);
  float* c0r = (float*)alloc(H_ * 4);
  float* c0z = (float*)alloc(H_ * 4);
  float* c0n = (float*)alloc(H_ * 4);
  float* c1r = (float*)alloc(H_ * 4);
  float* c1z = (float*)alloc(H_ * 4);
  float* c1n = (float*)alloc(H_ * 4);
  float* chn = (float*)alloc(H_ * 4);
  float* dvec = (float*)alloc(H3_ * 4);
  float* evec = (float*)alloc(H3_ * 4);
  float* sig_tmp = (float*)alloc(Z_ * 4);
  float* invsig = (float*)alloc(256);
  int* bar_cnt   = (int*)alloc(256);
  int* bar_sense = (int*)alloc(256);
  (void)in_sizes; (void)n_in; (void)out_size; (void)ws_size;

  initk<<<1, 64, 0, stream>>>(bar_cnt, bar_sense);
  mega<<<NWG, 512, 0, stream>>>(
      z, fc_w, fc_b, fc_u, w_ih, w_hh, b_ih, b_hh, lin_w, lin_b,
      w_ih_q, w_hhn_q, lin_w_q, lin_wT_q, fc_w_q, z_q, x0_q,
      Wsum_r, Wsum_z, Wn_c, Hhist, h_f32, outs,
      c0r, c0z, c0n, c1r, c1z, c1n, chn, dvec, evec, sig_tmp, invsig,
      out, bar_cnt, bar_sense);
}

// Round 6
// 482.990 us; speedup vs baseline: 2.5018x; 2.5018x over previous
//
#include <hip/hip_runtime.h>
#include <hip/hip_bf16.h>
#include <cstdint>
#include <cstddef>

#define B_  256
#define Z_  512
#define H_  2048
#define T_  16
#define H3_ 6144

using short8  = __attribute__((ext_vector_type(8))) short;
using bf16x8  = __attribute__((ext_vector_type(8))) __bf16;
using f32x4   = __attribute__((ext_vector_type(4))) float;
using f32x16  = __attribute__((ext_vector_type(16))) float;

__device__ __forceinline__ f32x4 mfma_bf16(short8 a, short8 b, f32x4 c) {
  return __builtin_amdgcn_mfma_f32_16x16x32_bf16(
      __builtin_bit_cast(bf16x8, a), __builtin_bit_cast(bf16x8, b), c, 0, 0, 0);
}
__device__ __forceinline__ f32x16 mfma_bf16_32(short8 a, short8 b, f32x16 c) {
  return __builtin_amdgcn_mfma_f32_32x32x16_bf16(
      __builtin_bit_cast(bf16x8, a), __builtin_bit_cast(bf16x8, b), c, 0, 0, 0);
}

__device__ __forceinline__ unsigned short f2bf(float f) {
  unsigned int u = __builtin_bit_cast(unsigned int, f);
  u = (u + 0x7FFFu + ((u >> 16) & 1u)) >> 16;
  return (unsigned short)u;
}

__device__ __forceinline__ float sigmoidf_(float x) { return 1.0f / (1.0f + __expf(-x)); }

// LDS XOR swizzle: tiles are [rows][64] bf16 (128 B rows = 8x16B chunks).
__device__ __forceinline__ int swz(int row, int chunk) {
  return row * 64 + ((chunk ^ (row & 7)) << 3);   // ushort element offset
}

// ---------------------------------------------------------------------------
// GRU step v3. Tile: M=32 (m_idx 0..7) x 128 gate-cols (32 h-cols x 4 gates).
// Grid 512 (2 WGs/CU), 256 thr, 4 waves; wave w computes gate w's 32x32 tile
// via mfma_32x32x16. Gates exchanged through padded LDS for fused epilogue.
// XCD swizzle: xcd = colgrp % 8 so a colgroup's 8 m-sharers are co-XCD.
// ---------------------------------------------------------------------------
__global__ __launch_bounds__(256, 2) void gru_step3(
    const unsigned short* __restrict__ A, int K,
    const unsigned short* __restrict__ Wr,
    const unsigned short* __restrict__ Wz,
    const unsigned short* __restrict__ Wn,
    const unsigned short* __restrict__ Whn,
    const float* __restrict__ cr, const float* __restrict__ cz,
    const float* __restrict__ cn, const float* __restrict__ chn,
    float hn_scale,
    const float* __restrict__ h_old,
    float* __restrict__ h_new,
    unsigned short* __restrict__ h_hist)
{
  __shared__ __align__(16) unsigned short sbuf[2][10240]; // [A 2048 | W 8192] ush
  __shared__ float LDSf[4][32][33];                        // gate exchange
  const int bid = blockIdx.x, tid = threadIdx.x;
  const int xcd = bid & 7, rst = bid >> 3;
  const int m_idx = rst & 7, gg = rst >> 3;
  const int grp = gg * 8 + xcd;            // [0,64) h-col group
  const int m0 = m_idx * 32;
  const int gh0 = grp * 32;                // h-col base
  const int wave = tid >> 6, lane = tid & 63;
  const int lh = lane >> 5, l31 = lane & 31;

  // staging maps: A: 1 dwordx4/thread; W: 4 consecutive dwordx4/thread.
  const int arow = tid >> 3, achk = tid & 7;
  const int wrow = tid >> 1, wc0 = (tid & 1) * 4;
  const unsigned short* wsrc =
      (wrow < 32) ? Wr : (wrow < 64) ? Wz : (wrow < 96) ? Wn : Whn; // wave-uniform
  const size_t aoff = (size_t)(m0 + arow) * K + achk * 8;
  const size_t woff = (size_t)(gh0 + (wrow & 31)) * K + wc0 * 8;
  const int sa_d = swz(arow, achk);
  const int sw_d0 = 2048 + swz(wrow, wc0 + 0);
  const int sw_d1 = 2048 + swz(wrow, wc0 + 1);
  const int sw_d2 = 2048 + swz(wrow, wc0 + 2);
  const int sw_d3 = 2048 + swz(wrow, wc0 + 3);

  uint4 Aa, Aw0, Aw1, Aw2, Aw3;   // prefetch set A (even chunks)
  uint4 Ba, Bw0, Bw1, Bw2, Bw3;   // prefetch set B (odd chunks)

#define LDSET(a, w0, w1, w2, w3, k0)                      \
  {                                                        \
    const int kk_ = (k0);                                  \
    a  = *(const uint4*)(A    + aoff + kk_);               \
    w0 = *(const uint4*)(wsrc + woff + kk_);               \
    w1 = *(const uint4*)(wsrc + woff + kk_ + 8);           \
    w2 = *(const uint4*)(wsrc + woff + kk_ + 16);          \
    w3 = *(const uint4*)(wsrc + woff + kk_ + 24);          \
  }
#define STAGE(s, a, w0, w1, w2, w3)                        \
  {                                                        \
    unsigned short* b_ = sbuf[s];                          \
    *(uint4*)(b_ + sa_d)  = a;                             \
    *(uint4*)(b_ + sw_d0) = w0;                            \
    *(uint4*)(b_ + sw_d1) = w1;                            \
    *(uint4*)(b_ + sw_d2) = w2;                            \
    *(uint4*)(b_ + sw_d3) = w3;                            \
  }

  f32x16 acc = {};
#define COMP(s)                                                            \
  {                                                                        \
    const unsigned short* b_ = sbuf[s];                                    \
    _Pragma("unroll")                                                      \
    for (int ks = 0; ks < 4; ++ks) {                                       \
      short8 af = *(const short8*)(b_ + swz(l31, ks * 2 + lh));            \
      short8 wf = *(const short8*)(b_ + 2048 + swz(wave * 32 + l31, ks * 2 + lh)); \
      acc = mfma_bf16_32(af, wf, acc);                                     \
    }                                                                      \
  }

  const int nIter = K >> 6;     // 64-k chunks; 32 (K=2048) or 8 (K=512), even
  LDSET(Aa, Aw0, Aw1, Aw2, Aw3, 0);
  LDSET(Ba, Bw0, Bw1, Bw2, Bw3, 64);
  for (int it = 0; it < nIter; it += 2) {
    STAGE(0, Aa, Aw0, Aw1, Aw2, Aw3);
    __syncthreads();
    { const int kn = (it + 2 < nIter) ? ((it + 2) << 6) : 0;
      LDSET(Aa, Aw0, Aw1, Aw2, Aw3, kn); }
    COMP(0);
    STAGE(1, Ba, Bw0, Bw1, Bw2, Bw3);
    __syncthreads();
    { const int kn = (it + 3 < nIter) ? ((it + 3) << 6) : 64;
      LDSET(Ba, Bw0, Bw1, Bw2, Bw3, kn); }
    COMP(1);
  }
#undef LDSET
#undef STAGE
#undef COMP

  // ---- gate exchange: C layout col=lane&31, row=(reg&3)+8*(reg>>2)+4*(lane>>5)
#pragma unroll
  for (int reg = 0; reg < 16; ++reg) {
    const int row = (reg & 3) + 8 * (reg >> 2) + 4 * lh;
    LDSf[wave][row][l31] = acc[reg];
  }
  __syncthreads();
  {
    const int row = tid >> 3, c0 = (tid & 7) * 4;
    const int grow = m0 + row;
#pragma unroll
    for (int j = 0; j < 4; ++j) {
      const int col = c0 + j;
      const int gcol = gh0 + col;
      const float R   = sigmoidf_(LDSf[0][row][col] + cr[gcol]);
      const float U   = sigmoidf_(LDSf[1][row][col] + cz[gcol]);
      const float HNv = hn_scale * LDSf[3][row][col] + chn[gcol];
      const float Nv  = tanhf(LDSf[2][row][col] + cn[gcol] + R * HNv);
      const float ho  = h_old ? h_old[(size_t)grow * H_ + gcol] : 0.0f;
      const float hv  = (1.0f - U) * Nv + U * ho;
      h_new[(size_t)grow * H_ + gcol]  = hv;
      h_hist[(size_t)grow * H_ + gcol] = f2bf(hv);
    }
  }
}

// ---------------------------------------------------------------------------
// Generic bf16 GEMM, C = A @ B^T (+add)(+bias)(*scale). WG tile 32x64.
// Grid = (M/32, N/64). Used only for the small x0 GEMM (M=256).
// ---------------------------------------------------------------------------
__global__ __launch_bounds__(256) void gemm_bt(
    const unsigned short* __restrict__ A,
    const unsigned short* __restrict__ Bw,
    int K,
    const float* __restrict__ addsrc, int add_ld,
    const float* __restrict__ bias,
    const float* __restrict__ scale_ptr,
    unsigned short* __restrict__ out_bf,
    float* __restrict__ out_f, int ldo)
{
  __shared__ unsigned short sA[32 * 64];
  __shared__ unsigned short sB[64 * 64];
  const int tid  = threadIdx.x;
  const int m0   = blockIdx.x * 32, n0 = blockIdx.y * 64;
  const int wave = tid >> 6, lane = tid & 63;
  const int wr = wave & 1, wc = wave >> 1;
  const int q = lane >> 4, c16 = lane & 15;
  const int lr = tid >> 3, lc8 = tid & 7;
  f32x4 acc0 = {}, acc1 = {};
  const size_t rowA  = (size_t)(m0 + lr) * K;
  const size_t rowB0 = (size_t)(n0 + lr) * K;
  const size_t rowB1 = (size_t)(n0 + 32 + lr) * K;
  for (int k0 = 0; k0 < K; k0 += 64) {
    const int gc = k0 + lc8 * 8;
    uint4 ra  = *(const uint4*)(A  + rowA  + gc);
    uint4 rb0 = *(const uint4*)(Bw + rowB0 + gc);
    uint4 rb1 = *(const uint4*)(Bw + rowB1 + gc);
    __syncthreads();
    *(uint4*)(sA + swz(lr, lc8))      = ra;
    *(uint4*)(sB + swz(lr, lc8))      = rb0;
    *(uint4*)(sB + swz(32 + lr, lc8)) = rb1;
    __syncthreads();
#pragma unroll
    for (int kk = 0; kk < 2; ++kk) {
      const int arow = wr * 16 + c16;
      short8 af = *(const short8*)(sA + swz(arow, kk * 4 + q));
      const int brow = wc * 32 + c16;
      short8 b0 = *(const short8*)(sB + swz(brow, kk * 4 + q));
      acc0 = mfma_bf16(af, b0, acc0);
      short8 b1 = *(const short8*)(sB + swz(brow + 16, kk * 4 + q));
      acc1 = mfma_bf16(af, b1, acc1);
    }
  }
  const float scale = scale_ptr ? *scale_ptr : 1.0f;
#pragma unroll
  for (int cf = 0; cf < 2; ++cf) {
    f32x4 a = cf ? acc1 : acc0;
#pragma unroll
    for (int v = 0; v < 4; ++v) {
      const int row = m0 + wr * 16 + q * 4 + v;
      const int col = n0 + wc * 32 + cf * 16 + c16;
      float val = a[v] * scale;
      if (addsrc) val += addsrc[(size_t)row * add_ld + col];
      if (bias)   val += bias[col];
      if (out_f)  out_f[(size_t)row * ldo + col] = val;
      if (out_bf) out_bf[(size_t)row * ldo + col] = f2bf(val);
    }
  }
}

// ---------------------------------------------------------------------------
// 64x64-tile bf16 GEMM, C = A @ B^T (+add)(+bias). Grid = (M/64, N/64).
// 4 waves of 32x32. Reg-prefetch pipeline.
// ---------------------------------------------------------------------------
__global__ __launch_bounds__(256) void gemm_bt64(
    const unsigned short* __restrict__ A,
    const unsigned short* __restrict__ Bw,
    int K,
    const float* __restrict__ addsrc, int add_ld,
    const float* __restrict__ bias,
    unsigned short* __restrict__ out_bf,
    float* __restrict__ out_f, int ldo)
{
  __shared__ unsigned short sA[64 * 64];
  __shared__ unsigned short sB[64 * 64];
  const int tid  = threadIdx.x;
  const int m0   = blockIdx.x * 64, n0 = blockIdx.y * 64;
  const int wave = tid >> 6, lane = tid & 63;
  const int wr = wave & 1, wc = wave >> 1;
  const int q = lane >> 4, c16 = lane & 15;
  const int lr = tid >> 3, lc8 = tid & 7;
  f32x4 acc[2][2] = {};
  const size_t aoff = (size_t)(m0 + lr) * K;
  const size_t boff = (size_t)(n0 + lr) * K;
  const size_t s32  = (size_t)32 * K;

  uint4 ra0, ra1, rb0, rb1;
  auto LOAD = [&](int k0) {
    const int gc = k0 + lc8 * 8;
    ra0 = *(const uint4*)(A  + aoff + gc);
    ra1 = *(const uint4*)(A  + aoff + s32 + gc);
    rb0 = *(const uint4*)(Bw + boff + gc);
    rb1 = *(const uint4*)(Bw + boff + s32 + gc);
  };

  const int nIter = K >> 6;
  LOAD(0);
  for (int it = 0; it < nIter; ++it) {
    __syncthreads();
    *(uint4*)(sA + swz(lr, lc8))      = ra0;
    *(uint4*)(sA + swz(lr + 32, lc8)) = ra1;
    *(uint4*)(sB + swz(lr, lc8))      = rb0;
    *(uint4*)(sB + swz(lr + 32, lc8)) = rb1;
    __syncthreads();
    if (it + 1 < nIter) LOAD((it + 1) << 6);
#pragma unroll
    for (int kk = 0; kk < 2; ++kk) {
      short8 af0 = *(const short8*)(sA + swz(wr * 32 + c16,      kk * 4 + q));
      short8 af1 = *(const short8*)(sA + swz(wr * 32 + 16 + c16, kk * 4 + q));
      short8 bf0 = *(const short8*)(sB + swz(wc * 32 + c16,      kk * 4 + q));
      short8 bf1 = *(const short8*)(sB + swz(wc * 32 + 16 + c16, kk * 4 + q));
      acc[0][0] = mfma_bf16(af0, bf0, acc[0][0]);
      acc[0][1] = mfma_bf16(af0, bf1, acc[0][1]);
      acc[1][0] = mfma_bf16(af1, bf0, acc[1][0]);
      acc[1][1] = mfma_bf16(af1, bf1, acc[1][1]);
    }
  }
#pragma unroll
  for (int i = 0; i < 2; ++i) {
#pragma unroll
    for (int j = 0; j < 2; ++j) {
#pragma unroll
      for (int v = 0; v < 4; ++v) {
        const int row = m0 + wr * 32 + i * 16 + q * 4 + v;
        const int col = n0 + wc * 32 + j * 16 + c16;
        float val = acc[i][j][v];
        if (addsrc) val += addsrc[(size_t)row * add_ld + col];
        if (bias)   val += bias[col];
        if (out_f)  out_f[(size_t)row * ldo + col] = val;
        if (out_bf) out_bf[(size_t)row * ldo + col] = f2bf(val);
      }
    }
  }
}

// ---------------------------------------------------------------------------
// merged quantization of all bf16 operands (one launch)
// ---------------------------------------------------------------------------
__global__ __launch_bounds__(256) void quant_all(
    const float* __restrict__ z, const float* __restrict__ fc_w,
    const float* __restrict__ w_ih, const float* __restrict__ w_hh,
    const float* __restrict__ lin_w,
    unsigned short* __restrict__ z_q, unsigned short* __restrict__ fc_w_q,
    unsigned short* __restrict__ w_ih_q, unsigned short* __restrict__ w_hhn_q,
    unsigned short* __restrict__ lin_w_q)
{
  const int i = blockIdx.x * 256 + threadIdx.x;
  if (i >= 2195456) return;
  const float4* src; ushort4* dst; int idx;
  if (i < 32768)        { src = (const float4*)z;     dst = (ushort4*)z_q;     idx = i; }
  else if (i < 98304)   { src = (const float4*)fc_w;  dst = (ushort4*)fc_w_q;  idx = i - 32768; }
  else if (i < 884736)  { src = (const float4*)w_ih;  dst = (ushort4*)w_ih_q;  idx = i - 98304; }
  else if (i < 1933312) { src = (const float4*)(w_hh + (size_t)2 * H_ * H_);
                          dst = (ushort4*)w_hhn_q;    idx = i - 884736; }
  else                  { src = (const float4*)lin_w; dst = (ushort4*)lin_w_q; idx = i - 1933312; }
  float4 v = src[idx];
  ushort4 o; o.x = f2bf(v.x); o.y = f2bf(v.y); o.z = f2bf(v.z); o.w = f2bf(v.w);
  dst[idx] = o;
}

// lin_w [512][2048] f32 -> lin_wT [2048][512] bf16
__global__ __launch_bounds__(256) void transq(const float* __restrict__ s,
                                              unsigned short* __restrict__ d) {
  __shared__ float tile[32][33];
  const int tx = threadIdx.x & 31, ty = threadIdx.x >> 5;
  const int k0 = blockIdx.x * 32, z0 = blockIdx.y * 32;
#pragma unroll
  for (int j = 0; j < 4; ++j)
    tile[ty + j * 8][tx] = s[(size_t)(z0 + ty + j * 8) * H_ + k0 + tx];
  __syncthreads();
#pragma unroll
  for (int j = 0; j < 4; ++j)
    d[(size_t)(k0 + ty + j * 8) * Z_ + z0 + tx] = f2bf(tile[tx][ty + j * 8]);
}

// t1 = W^T u.  grid 8, block 256 (4 waves x 128 rows each).
__global__ void sigma1(const float* __restrict__ W, const float* __restrict__ u,
                       float* __restrict__ t1) {
  __shared__ float part[4][64];
  const int lane = threadIdx.x & 63, wv = threadIdx.x >> 6;
  const int col = blockIdx.x * 64 + lane;
  float s = 0.f;
  for (int r = wv * 128; r < wv * 128 + 128; ++r)
    s += W[(size_t)r * Z_ + col] * u[r];
  part[wv][lane] = s;
  __syncthreads();
  if (wv == 0)
    t1[col] = part[0][lane] + part[1][lane] + part[2][lane] + part[3][lane];
}

__global__ void sigma1b(const float* __restrict__ t1, float* __restrict__ invn) {
  __shared__ float red[256];
  int t = threadIdx.x;
  float v0 = t1[t], v1 = t1[t + 256];
  red[t] = v0 * v0 + v1 * v1;
  __syncthreads();
  for (int s = 128; s > 0; s >>= 1) {
    if (t < s) red[t] += red[t + s];
    __syncthreads();
  }
  if (t == 0) invn[0] = 1.0f / (sqrtf(red[0]) + 1e-12f);
}

// t2 = W @ (t1 * invn).  grid 128, block 256 (wave per row).
__global__ void sigma2(const float* __restrict__ W, const float* __restrict__ t1,
                       const float* __restrict__ invn, float* __restrict__ t2) {
  const int lane = threadIdx.x & 63, wv = threadIdx.x >> 6;
  const int row = blockIdx.x * 4 + wv;
  float s = 0.f;
  for (int c = lane; c < Z_; c += 64) s += W[(size_t)row * Z_ + c] * t1[c];
#pragma unroll
  for (int off = 32; off > 0; off >>= 1) s += __shfl_down(s, off);
  if (lane == 0) t2[row] = s * invn[0];
}

__global__ void sigma3(const float* __restrict__ t2, float* __restrict__ inv_sig) {
  __shared__ float red[256];
  int t = threadIdx.x;
  float v0 = t2[t], v1 = t2[t + 256];
  red[t] = v0 * v0 + v1 * v1;
  __syncthreads();
  for (int s = 128; s > 0; s >>= 1) {
    if (t < s) red[t] += red[t + s];
    __syncthreads();
  }
  if (t == 0) {
    float s2  = red[0];
    float sig = s2 / (sqrtf(s2) + 1e-12f);
    inv_sig[0] = 1.0f / sig;
  }
}

// dvec[row] = dot(w_ih[row], lin_b) for row in [0, 6144)
__global__ __launch_bounds__(256) void dots_k(const float* __restrict__ w,
                                              const float* __restrict__ lb,
                                              float* __restrict__ dvec) {
  const int wave = threadIdx.x >> 6, lane = threadIdx.x & 63;
#pragma unroll
  for (int i = 0; i < 4; ++i) {
    int row = blockIdx.x * 16 + wave * 4 + i;
    float s = 0.f;
    for (int c = lane; c < Z_; c += 64) s += w[(size_t)row * Z_ + c] * lb[c];
#pragma unroll
    for (int off = 32; off > 0; off >>= 1) s += __shfl_down(s, off);
    if (lane == 0) dvec[row] = s;
  }
}

__global__ void consts_k(const float* __restrict__ b_ih, const float* __restrict__ b_hh,
                         const float* __restrict__ dvec,
                         float* __restrict__ c0r, float* __restrict__ c0z,
                         float* __restrict__ c0n,
                         float* __restrict__ c1r, float* __restrict__ c1z,
                         float* __restrict__ c1n, float* __restrict__ chn) {
  int j = blockIdx.x * 256 + threadIdx.x;
  float br = b_ih[j], bz = b_ih[H_ + j], bn = b_ih[2 * H_ + j];
  float hr = b_hh[j], hz = b_hh[H_ + j], hn = b_hh[2 * H_ + j];
  c0r[j] = br + hr; c0z[j] = bz + hz; c0n[j] = bn; chn[j] = hn;
  c1r[j] = br + hr + dvec[j];
  c1z[j] = bz + hz + dvec[H_ + j];
  c1n[j] = bn + dvec[2 * H_ + j];
}

// BN over batch per (t,z) + transpose [T,B,Z] -> [B,T,Z]. Grid (16, 8).
__global__ __launch_bounds__(256) void bn_k(const float* __restrict__ outs,
                                            float* __restrict__ y) {
  __shared__ float s_sum[4][64], s_sq[4][64], s_mean[64], s_inv[64];
  const int t = blockIdx.x, zb = blockIdx.y;
  const int zl = threadIdx.x & 63, bp = threadIdx.x >> 6;
  const int z = zb * 64 + zl;
  float sum = 0.f, sq = 0.f;
  for (int b = bp * 64; b < bp * 64 + 64; ++b) {
    float v = outs[(size_t)(t * 256 + b) * Z_ + z];
    sum += v; sq += v * v;
  }
  s_sum[bp][zl] = sum; s_sq[bp][zl] = sq;
  __syncthreads();
  if (bp == 0) {
    float S = s_sum[0][zl] + s_sum[1][zl] + s_sum[2][zl] + s_sum[3][zl];
    float Q = s_sq[0][zl] + s_sq[1][zl] + s_sq[2][zl] + s_sq[3][zl];
    float mean = S * (1.0f / 256.0f);
    float var  = Q * (1.0f / 256.0f) - mean * mean;
    s_mean[zl] = mean;
    s_inv[zl]  = rsqrtf(var + 1e-5f);
  }
  __syncthreads();
  const float mean = s_mean[zl], inv = s_inv[zl];
  for (int b = bp * 64; b < bp * 64 + 64; ++b) {
    float v = outs[(size_t)(t * 256 + b) * Z_ + z];
    y[(size_t)(b * T_ + t) * Z_ + z] = (v - mean) * inv;
  }
}

// ---------------------------------------------------------------------------
extern "C" void kernel_launch(void* const* d_in, const int* in_sizes, int n_in,
                              void* d_out, int out_size, void* d_ws, size_t ws_size,
                              hipStream_t stream) {
  const float* z     = (const float*)d_in[0];
  const float* fc_w  = (const float*)d_in[1];
  const float* fc_b  = (const float*)d_in[2];
  const float* fc_u  = (const float*)d_in[3];
  const float* w_ih  = (const float*)d_in[4];
  const float* w_hh  = (const float*)d_in[5];
  const float* b_ih  = (const float*)d_in[6];
  const float* b_hh  = (const float*)d_in[7];
  const float* lin_w = (const float*)d_in[8];
  const float* lin_b = (const float*)d_in[9];
  float* out = (float*)d_out;

  char* ws = (char*)d_ws;
  size_t off = 0;
  auto alloc = [&](size_t bytes) -> void* {
    off = (off + 255) & ~(size_t)255;
    void* p = ws + off;
    off += bytes;
    return p;
  };
  unsigned short* w_ih_q   = (unsigned short*)alloc((size_t)H3_ * Z_ * 2);
  unsigned short* w_hhn_q  = (unsigned short*)alloc((size_t)H_ * H_ * 2);
  unsigned short* lin_w_q  = (unsigned short*)alloc((size_t)Z_ * H_ * 2);
  unsigned short* lin_wT_q = (unsigned short*)alloc((size_t)Z_ * H_ * 2);
  unsigned short* fc_w_q   = (unsigned short*)alloc((size_t)Z_ * Z_ * 2);
  unsigned short* z_q      = (unsigned short*)alloc((size_t)B_ * Z_ * 2);
  unsigned short* x0_q     = (unsigned short*)alloc((size_t)B_ * Z_ * 2);
  unsigned short* Wsum_r   = (unsigned short*)alloc((size_t)H_ * H_ * 2);
  unsigned short* Wsum_z   = (unsigned short*)alloc((size_t)H_ * H_ * 2);
  unsigned short* Wn_c     = (unsigned short*)alloc((size_t)H_ * H_ * 2);
  unsigned short* Hhist    = (unsigned short*)alloc((size_t)T_ * B_ * H_ * 2);
  float* h_f32 = (float*)alloc((size_t)2 * B_ * H_ * 4);
  float* outs  = (float*)alloc((size_t)T_ * B_ * Z_ * 4);
  float* c0r = (float*)alloc(H_ * 4);
  float* c0z = (float*)alloc(H_ * 4);
  float* c0n = (float*)alloc(H_ * 4);
  float* c1r = (float*)alloc(H_ * 4);
  float* c1z = (float*)alloc(H_ * 4);
  float* c1n = (float*)alloc(H_ * 4);
  float* chn = (float*)alloc(H_ * 4);
  float* dvec = (float*)alloc(H3_ * 4);
  float* t1v = (float*)alloc(Z_ * 4);
  float* t2v = (float*)alloc(Z_ * 4);
  float* invn = (float*)alloc(256);
  float* invsig = (float*)alloc(256);
  (void)in_sizes; (void)n_in; (void)out_size; (void)ws_size;

  quant_all<<<dim3((2195456 + 255) / 256), 256, 0, stream>>>(
      z, fc_w, w_ih, w_hh, lin_w, z_q, fc_w_q, w_ih_q, w_hhn_q, lin_w_q);
  transq<<<dim3(64, 16), 256, 0, stream>>>(lin_w, lin_wT_q);
  sigma1<<<8, 256, 0, stream>>>(fc_w, fc_u, t1v);
  sigma1b<<<1, 256, 0, stream>>>(t1v, invn);
  sigma2<<<128, 256, 0, stream>>>(fc_w, t1v, invn, t2v);
  sigma3<<<1, 256, 0, stream>>>(t2v, invsig);
  dots_k<<<384, 256, 0, stream>>>(w_ih, lin_b, dvec);
  consts_k<<<8, 256, 0, stream>>>(b_ih, b_hh, dvec, c0r, c0z, c0n, c1r, c1z, c1n, chn);

  // x0 = (z @ fc_w^T) * inv_sigma + fc_b   -> bf16
  gemm_bt<<<dim3(B_ / 32, Z_ / 64), 256, 0, stream>>>(
      z_q, fc_w_q, Z_, nullptr, 0, fc_b, invsig, x0_q, nullptr, Z_);

  // W_comb_g = w_ih_g @ lin_w (+ w_hh_g for r,z) -> bf16 [2048][2048]
  for (int g = 0; g < 3; ++g) {
    const float* adds = (g < 2) ? (w_hh + (size_t)g * H_ * H_) : nullptr;
    unsigned short* outw = (g == 0) ? Wsum_r : (g == 1) ? Wsum_z : Wn_c;
    gemm_bt64<<<dim3(H_ / 64, H_ / 64), 256, 0, stream>>>(
        w_ih_q + (size_t)g * H_ * Z_, lin_wT_q, Z_, adds, H_, nullptr,
        outw, nullptr, H_);
  }

  for (int t = 0; t < T_; ++t) {
    if (t == 0) {
      gru_step3<<<512, 256, 0, stream>>>(
          x0_q, Z_,
          w_ih_q, w_ih_q + (size_t)H_ * Z_, w_ih_q + (size_t)2 * H_ * Z_,
          w_ih_q /* dummy, scaled by 0 */,
          c0r, c0z, c0n, chn, 0.0f, nullptr, h_f32, Hhist);
    } else {
      gru_step3<<<512, 256, 0, stream>>>(
          Hhist + (size_t)(t - 1) * B_ * H_, H_,
          Wsum_r, Wsum_z, Wn_c, w_hhn_q,
          c1r, c1z, c1n, chn, 1.0f,
          h_f32 + (size_t)((t - 1) & 1) * B_ * H_,
          h_f32 + (size_t)(t & 1) * B_ * H_,
          Hhist + (size_t)t * B_ * H_);
    }
  }

  // outs[t*256+b][z] = Hhist[t][b] @ lin_w^T + lin_b   (f32)
  gemm_bt64<<<dim3(T_ * B_ / 64, Z_ / 64), 256, 0, stream>>>(
      Hhist, lin_w_q, H_, nullptr, 0, lin_b, nullptr, outs, Z_);

  bn_k<<<dim3(T_, Z_ / 64), 256, 0, stream>>>(outs, out);
}

// Round 7
// 402.687 us; speedup vs baseline: 3.0007x; 1.1994x over previous
//
#include <hip/hip_runtime.h>
#include <hip/hip_bf16.h>
#include <cstdint>
#include <cstddef>

#define B_  256
#define Z_  512
#define H_  2048
#define T_  16
#define H3_ 6144

using short8  = __attribute__((ext_vector_type(8))) short;
using bf16x8  = __attribute__((ext_vector_type(8))) __bf16;
using f32x4   = __attribute__((ext_vector_type(4))) float;
using f32x16  = __attribute__((ext_vector_type(16))) float;

__device__ __forceinline__ f32x4 mfma_bf16(short8 a, short8 b, f32x4 c) {
  return __builtin_amdgcn_mfma_f32_16x16x32_bf16(
      __builtin_bit_cast(bf16x8, a), __builtin_bit_cast(bf16x8, b), c, 0, 0, 0);
}
__device__ __forceinline__ f32x16 mfma_bf16_32(short8 a, short8 b, f32x16 c) {
  return __builtin_amdgcn_mfma_f32_32x32x16_bf16(
      __builtin_bit_cast(bf16x8, a), __builtin_bit_cast(bf16x8, b), c, 0, 0, 0);
}

__device__ __forceinline__ unsigned short f2bf(float f) {
  unsigned int u = __builtin_bit_cast(unsigned int, f);
  u = (u + 0x7FFFu + ((u >> 16) & 1u)) >> 16;
  return (unsigned short)u;
}

__device__ __forceinline__ float sigmoidf_(float x) { return 1.0f / (1.0f + __expf(-x)); }

// LDS XOR swizzle: tiles are [rows][64] bf16 (128 B rows = 8x16B chunks).
__device__ __forceinline__ int swz(int row, int chunk) {
  return row * 64 + ((chunk ^ (row & 7)) << 3);   // ushort element offset
}

// ---------------------------------------------------------------------------
// GRU step v4. Tile: M=64 (m_idx 0..3) x 128 gate-cols (32 h-cols x 4 gates).
// Grid 256 (1 WG/CU), 512 thr, 8 waves = (gate 4) x (m-half 2); each wave one
// 32x32 tile via mfma_32x32x16. M=64 halves L2 weight re-reads vs v3
// (4 m-sharers instead of 8): per-XCD L2 traffic 40 -> 24 MB/step.
// XCD swizzle: xcd = colgrp % 8; a colgroup's 4 m-sharers are co-XCD.
// ---------------------------------------------------------------------------
__global__ __launch_bounds__(512, 1) void gru_step4(
    const unsigned short* __restrict__ A, int K,
    const unsigned short* __restrict__ Wr,
    const unsigned short* __restrict__ Wz,
    const unsigned short* __restrict__ Wn,
    const unsigned short* __restrict__ Whn,
    const float* __restrict__ cr, const float* __restrict__ cz,
    const float* __restrict__ cn, const float* __restrict__ chn,
    float hn_scale,
    const float* __restrict__ h_old,
    float* __restrict__ h_new,
    unsigned short* __restrict__ h_hist)
{
  // A region: 64x64 ush (8KB) at [0,4096); W region: 128x64 (16KB) at [4096,12288)
  __shared__ __align__(16) unsigned short sbuf[2][12288];   // 48 KB
  __shared__ float LDSf[4][64][33];                          // 33.8 KB exchange
  const int bid = blockIdx.x, tid = threadIdx.x;
  const int xcd = bid & 7, rst = bid >> 3;
  const int m_idx = rst & 3, gg = rst >> 2;
  const int grp = gg * 8 + xcd;            // [0,64) h-col group
  const int m0 = m_idx * 64;
  const int gh0 = grp * 32;                // h-col base
  const int wave = tid >> 6, lane = tid & 63;
  const int gate = wave & 3, mh = wave >> 2;
  const int lh = lane >> 5, l31 = lane & 31;

  // staging maps: A: 1 dwordx4/thread (64 rows x 8 chunks);
  //               W: 2 consecutive dwordx4/thread (128 rows x 8 chunks).
  const int arow = tid >> 3, achk = tid & 7;
  const int wrow = tid >> 2, wc0 = (tid & 3) * 2;
  const unsigned short* wsrc =
      (wrow < 32) ? Wr : (wrow < 64) ? Wz : (wrow < 96) ? Wn : Whn; // wave-uniform
  const size_t aoff = (size_t)(m0 + arow) * K + achk * 8;
  const size_t woff = (size_t)(gh0 + (wrow & 31)) * K + wc0 * 8;
  const int sa_d  = swz(arow, achk);
  const int sw_d0 = 4096 + swz(wrow, wc0 + 0);
  const int sw_d1 = 4096 + swz(wrow, wc0 + 1);

  uint4 Aa, Aw0, Aw1;   // prefetch set A (even chunks)
  uint4 Ba, Bw0, Bw1;   // prefetch set B (odd chunks)

#define LDSET(a, w0, w1, k0)                               \
  {                                                        \
    const int kk_ = (k0);                                  \
    a  = *(const uint4*)(A    + aoff + kk_);               \
    w0 = *(const uint4*)(wsrc + woff + kk_);               \
    w1 = *(const uint4*)(wsrc + woff + kk_ + 8);           \
  }
#define STAGE(s, a, w0, w1)                                \
  {                                                        \
    unsigned short* b_ = sbuf[s];                          \
    *(uint4*)(b_ + sa_d)  = a;                             \
    *(uint4*)(b_ + sw_d0) = w0;                            \
    *(uint4*)(b_ + sw_d1) = w1;                            \
  }

  f32x16 acc = {};
#define COMP(s)                                                            \
  {                                                                        \
    const unsigned short* b_ = sbuf[s];                                    \
    _Pragma("unroll")                                                      \
    for (int ks = 0; ks < 4; ++ks) {                                       \
      short8 af = *(const short8*)(b_ + swz(mh * 32 + l31, ks * 2 + lh));  \
      short8 wf = *(const short8*)(b_ + 4096 + swz(gate * 32 + l31, ks * 2 + lh)); \
      acc = mfma_bf16_32(af, wf, acc);                                     \
    }                                                                      \
  }

  const int nIter = K >> 6;     // 64-k chunks; 32 (K=2048) or 8 (K=512), even
  LDSET(Aa, Aw0, Aw1, 0);
  LDSET(Ba, Bw0, Bw1, 64);
  for (int it = 0; it < nIter; it += 2) {
    STAGE(0, Aa, Aw0, Aw1);
    __syncthreads();
    { const int kn = (it + 2 < nIter) ? ((it + 2) << 6) : 0;
      LDSET(Aa, Aw0, Aw1, kn); }
    COMP(0);
    STAGE(1, Ba, Bw0, Bw1);
    __syncthreads();
    { const int kn = (it + 3 < nIter) ? ((it + 3) << 6) : 64;
      LDSET(Ba, Bw0, Bw1, kn); }
    COMP(1);
  }
#undef LDSET
#undef STAGE
#undef COMP

  // ---- gate exchange: C layout col=lane&31, row=(reg&3)+8*(reg>>2)+4*(lane>>5)
#pragma unroll
  for (int reg = 0; reg < 16; ++reg) {
    const int trow = (reg & 3) + 8 * (reg >> 2) + 4 * lh;
    LDSf[gate][mh * 32 + trow][l31] = acc[reg];
  }
  __syncthreads();
  {
    const int row = tid >> 3, c0 = (tid & 7) * 4;
    const int grow = m0 + row;
#pragma unroll
    for (int j = 0; j < 4; ++j) {
      const int col = c0 + j;
      const int gcol = gh0 + col;
      const float R   = sigmoidf_(LDSf[0][row][col] + cr[gcol]);
      const float U   = sigmoidf_(LDSf[1][row][col] + cz[gcol]);
      const float HNv = hn_scale * LDSf[3][row][col] + chn[gcol];
      const float Nv  = tanhf(LDSf[2][row][col] + cn[gcol] + R * HNv);
      const float ho  = h_old ? h_old[(size_t)grow * H_ + gcol] : 0.0f;
      const float hv  = (1.0f - U) * Nv + U * ho;
      h_new[(size_t)grow * H_ + gcol]  = hv;
      h_hist[(size_t)grow * H_ + gcol] = f2bf(hv);
    }
  }
}

// ---------------------------------------------------------------------------
// Generic bf16 GEMM, C = A @ B^T (+add)(+bias)(*scale). WG tile 32x64.
// Grid = (M/32, N/64). Used only for the small x0 GEMM (M=256).
// ---------------------------------------------------------------------------
__global__ __launch_bounds__(256) void gemm_bt(
    const unsigned short* __restrict__ A,
    const unsigned short* __restrict__ Bw,
    int K,
    const float* __restrict__ addsrc, int add_ld,
    const float* __restrict__ bias,
    const float* __restrict__ scale_ptr,
    unsigned short* __restrict__ out_bf,
    float* __restrict__ out_f, int ldo)
{
  __shared__ unsigned short sA[32 * 64];
  __shared__ unsigned short sB[64 * 64];
  const int tid  = threadIdx.x;
  const int m0   = blockIdx.x * 32, n0 = blockIdx.y * 64;
  const int wave = tid >> 6, lane = tid & 63;
  const int wr = wave & 1, wc = wave >> 1;
  const int q = lane >> 4, c16 = lane & 15;
  const int lr = tid >> 3, lc8 = tid & 7;
  f32x4 acc0 = {}, acc1 = {};
  const size_t rowA  = (size_t)(m0 + lr) * K;
  const size_t rowB0 = (size_t)(n0 + lr) * K;
  const size_t rowB1 = (size_t)(n0 + 32 + lr) * K;
  for (int k0 = 0; k0 < K; k0 += 64) {
    const int gc = k0 + lc8 * 8;
    uint4 ra  = *(const uint4*)(A  + rowA  + gc);
    uint4 rb0 = *(const uint4*)(Bw + rowB0 + gc);
    uint4 rb1 = *(const uint4*)(Bw + rowB1 + gc);
    __syncthreads();
    *(uint4*)(sA + swz(lr, lc8))      = ra;
    *(uint4*)(sB + swz(lr, lc8))      = rb0;
    *(uint4*)(sB + swz(32 + lr, lc8)) = rb1;
    __syncthreads();
#pragma unroll
    for (int kk = 0; kk < 2; ++kk) {
      const int arow = wr * 16 + c16;
      short8 af = *(const short8*)(sA + swz(arow, kk * 4 + q));
      const int brow = wc * 32 + c16;
      short8 b0 = *(const short8*)(sB + swz(brow, kk * 4 + q));
      acc0 = mfma_bf16(af, b0, acc0);
      short8 b1 = *(const short8*)(sB + swz(brow + 16, kk * 4 + q));
      acc1 = mfma_bf16(af, b1, acc1);
    }
  }
  const float scale = scale_ptr ? *scale_ptr : 1.0f;
#pragma unroll
  for (int cf = 0; cf < 2; ++cf) {
    f32x4 a = cf ? acc1 : acc0;
#pragma unroll
    for (int v = 0; v < 4; ++v) {
      const int row = m0 + wr * 16 + q * 4 + v;
      const int col = n0 + wc * 32 + cf * 16 + c16;
      float val = a[v] * scale;
      if (addsrc) val += addsrc[(size_t)row * add_ld + col];
      if (bias)   val += bias[col];
      if (out_f)  out_f[(size_t)row * ldo + col] = val;
      if (out_bf) out_bf[(size_t)row * ldo + col] = f2bf(val);
    }
  }
}

// ---------------------------------------------------------------------------
// 64x64-tile bf16 GEMM, C = A @ B^T (+add)(+bias). Grid = (M/64, N/64).
// 4 waves of 32x32. Reg-prefetch pipeline.
// ---------------------------------------------------------------------------
__global__ __launch_bounds__(256) void gemm_bt64(
    const unsigned short* __restrict__ A,
    const unsigned short* __restrict__ Bw,
    int K,
    const float* __restrict__ addsrc, int add_ld,
    const float* __restrict__ bias,
    unsigned short* __restrict__ out_bf,
    float* __restrict__ out_f, int ldo)
{
  __shared__ unsigned short sA[64 * 64];
  __shared__ unsigned short sB[64 * 64];
  const int tid  = threadIdx.x;
  const int m0   = blockIdx.x * 64, n0 = blockIdx.y * 64;
  const int wave = tid >> 6, lane = tid & 63;
  const int wr = wave & 1, wc = wave >> 1;
  const int q = lane >> 4, c16 = lane & 15;
  const int lr = tid >> 3, lc8 = tid & 7;
  f32x4 acc[2][2] = {};
  const size_t aoff = (size_t)(m0 + lr) * K;
  const size_t boff = (size_t)(n0 + lr) * K;
  const size_t s32  = (size_t)32 * K;

  uint4 ra0, ra1, rb0, rb1;
  auto LOAD = [&](int k0) {
    const int gc = k0 + lc8 * 8;
    ra0 = *(const uint4*)(A  + aoff + gc);
    ra1 = *(const uint4*)(A  + aoff + s32 + gc);
    rb0 = *(const uint4*)(Bw + boff + gc);
    rb1 = *(const uint4*)(Bw + boff + s32 + gc);
  };

  const int nIter = K >> 6;
  LOAD(0);
  for (int it = 0; it < nIter; ++it) {
    __syncthreads();
    *(uint4*)(sA + swz(lr, lc8))      = ra0;
    *(uint4*)(sA + swz(lr + 32, lc8)) = ra1;
    *(uint4*)(sB + swz(lr, lc8))      = rb0;
    *(uint4*)(sB + swz(lr + 32, lc8)) = rb1;
    __syncthreads();
    if (it + 1 < nIter) LOAD((it + 1) << 6);
#pragma unroll
    for (int kk = 0; kk < 2; ++kk) {
      short8 af0 = *(const short8*)(sA + swz(wr * 32 + c16,      kk * 4 + q));
      short8 af1 = *(const short8*)(sA + swz(wr * 32 + 16 + c16, kk * 4 + q));
      short8 bf0 = *(const short8*)(sB + swz(wc * 32 + c16,      kk * 4 + q));
      short8 bf1 = *(const short8*)(sB + swz(wc * 32 + 16 + c16, kk * 4 + q));
      acc[0][0] = mfma_bf16(af0, bf0, acc[0][0]);
      acc[0][1] = mfma_bf16(af0, bf1, acc[0][1]);
      acc[1][0] = mfma_bf16(af1, bf0, acc[1][0]);
      acc[1][1] = mfma_bf16(af1, bf1, acc[1][1]);
    }
  }
#pragma unroll
  for (int i = 0; i < 2; ++i) {
#pragma unroll
    for (int j = 0; j < 2; ++j) {
#pragma unroll
      for (int v = 0; v < 4; ++v) {
        const int row = m0 + wr * 32 + i * 16 + q * 4 + v;
        const int col = n0 + wc * 32 + j * 16 + c16;
        float val = acc[i][j][v];
        if (addsrc) val += addsrc[(size_t)row * add_ld + col];
        if (bias)   val += bias[col];
        if (out_f)  out_f[(size_t)row * ldo + col] = val;
        if (out_bf) out_bf[(size_t)row * ldo + col] = f2bf(val);
      }
    }
  }
}

// ---------------------------------------------------------------------------
// merged quantization of all bf16 operands (one launch)
// ---------------------------------------------------------------------------
__global__ __launch_bounds__(256) void quant_all(
    const float* __restrict__ z, const float* __restrict__ fc_w,
    const float* __restrict__ w_ih, const float* __restrict__ w_hh,
    const float* __restrict__ lin_w,
    unsigned short* __restrict__ z_q, unsigned short* __restrict__ fc_w_q,
    unsigned short* __restrict__ w_ih_q, unsigned short* __restrict__ w_hhn_q,
    unsigned short* __restrict__ lin_w_q)
{
  const int i = blockIdx.x * 256 + threadIdx.x;
  if (i >= 2195456) return;
  const float4* src; ushort4* dst; int idx;
  if (i < 32768)        { src = (const float4*)z;     dst = (ushort4*)z_q;     idx = i; }
  else if (i < 98304)   { src = (const float4*)fc_w;  dst = (ushort4*)fc_w_q;  idx = i - 32768; }
  else if (i < 884736)  { src = (const float4*)w_ih;  dst = (ushort4*)w_ih_q;  idx = i - 98304; }
  else if (i < 1933312) { src = (const float4*)(w_hh + (size_t)2 * H_ * H_);
                          dst = (ushort4*)w_hhn_q;    idx = i - 884736; }
  else                  { src = (const float4*)lin_w; dst = (ushort4*)lin_w_q; idx = i - 1933312; }
  float4 v = src[idx];
  ushort4 o; o.x = f2bf(v.x); o.y = f2bf(v.y); o.z = f2bf(v.z); o.w = f2bf(v.w);
  dst[idx] = o;
}

// lin_w [512][2048] f32 -> lin_wT [2048][512] bf16
__global__ __launch_bounds__(256) void transq(const float* __restrict__ s,
                                              unsigned short* __restrict__ d) {
  __shared__ float tile[32][33];
  const int tx = threadIdx.x & 31, ty = threadIdx.x >> 5;
  const int k0 = blockIdx.x * 32, z0 = blockIdx.y * 32;
#pragma unroll
  for (int j = 0; j < 4; ++j)
    tile[ty + j * 8][tx] = s[(size_t)(z0 + ty + j * 8) * H_ + k0 + tx];
  __syncthreads();
#pragma unroll
  for (int j = 0; j < 4; ++j)
    d[(size_t)(k0 + ty + j * 8) * Z_ + z0 + tx] = f2bf(tile[tx][ty + j * 8]);
}

// t1 = W^T u.  grid 8, block 256 (4 waves x 128 rows each).
__global__ void sigma1(const float* __restrict__ W, const float* __restrict__ u,
                       float* __restrict__ t1) {
  __shared__ float part[4][64];
  const int lane = threadIdx.x & 63, wv = threadIdx.x >> 6;
  const int col = blockIdx.x * 64 + lane;
  float s = 0.f;
  for (int r = wv * 128; r < wv * 128 + 128; ++r)
    s += W[(size_t)r * Z_ + col] * u[r];
  part[wv][lane] = s;
  __syncthreads();
  if (wv == 0)
    t1[col] = part[0][lane] + part[1][lane] + part[2][lane] + part[3][lane];
}

__global__ void sigma1b(const float* __restrict__ t1, float* __restrict__ invn) {
  __shared__ float red[256];
  int t = threadIdx.x;
  float v0 = t1[t], v1 = t1[t + 256];
  red[t] = v0 * v0 + v1 * v1;
  __syncthreads();
  for (int s = 128; s > 0; s >>= 1) {
    if (t < s) red[t] += red[t + s];
    __syncthreads();
  }
  if (t == 0) invn[0] = 1.0f / (sqrtf(red[0]) + 1e-12f);
}

// t2 = W @ (t1 * invn).  grid 128, block 256 (wave per row).
__global__ void sigma2(const float* __restrict__ W, const float* __restrict__ t1,
                       const float* __restrict__ invn, float* __restrict__ t2) {
  const int lane = threadIdx.x & 63, wv = threadIdx.x >> 6;
  const int row = blockIdx.x * 4 + wv;
  float s = 0.f;
  for (int c = lane; c < Z_; c += 64) s += W[(size_t)row * Z_ + c] * t1[c];
#pragma unroll
  for (int off = 32; off > 0; off >>= 1) s += __shfl_down(s, off);
  if (lane == 0) t2[row] = s * invn[0];
}

__global__ void sigma3(const float* __restrict__ t2, float* __restrict__ inv_sig) {
  __shared__ float red[256];
  int t = threadIdx.x;
  float v0 = t2[t], v1 = t2[t + 256];
  red[t] = v0 * v0 + v1 * v1;
  __syncthreads();
  for (int s = 128; s > 0; s >>= 1) {
    if (t < s) red[t] += red[t + s];
    __syncthreads();
  }
  if (t == 0) {
    float s2  = red[0];
    float sig = s2 / (sqrtf(s2) + 1e-12f);
    inv_sig[0] = 1.0f / sig;
  }
}

// dvec[row] = dot(w_ih[row], lin_b) for row in [0, 6144)
__global__ __launch_bounds__(256) void dots_k(const float* __restrict__ w,
                                              const float* __restrict__ lb,
                                              float* __restrict__ dvec) {
  const int wave = threadIdx.x >> 6, lane = threadIdx.x & 63;
#pragma unroll
  for (int i = 0; i < 4; ++i) {
    int row = blockIdx.x * 16 + wave * 4 + i;
    float s = 0.f;
    for (int c = lane; c < Z_; c += 64) s += w[(size_t)row * Z_ + c] * lb[c];
#pragma unroll
    for (int off = 32; off > 0; off >>= 1) s += __shfl_down(s, off);
    if (lane == 0) dvec[row] = s;
  }
}

__global__ void consts_k(const float* __restrict__ b_ih, const float* __restrict__ b_hh,
                         const float* __restrict__ dvec,
                         float* __restrict__ c0r, float* __restrict__ c0z,
                         float* __restrict__ c0n,
                         float* __restrict__ c1r, float* __restrict__ c1z,
                         float* __restrict__ c1n, float* __restrict__ chn) {
  int j = blockIdx.x * 256 + threadIdx.x;
  float br = b_ih[j], bz = b_ih[H_ + j], bn = b_ih[2 * H_ + j];
  float hr = b_hh[j], hz = b_hh[H_ + j], hn = b_hh[2 * H_ + j];
  c0r[j] = br + hr; c0z[j] = bz + hz; c0n[j] = bn; chn[j] = hn;
  c1r[j] = br + hr + dvec[j];
  c1z[j] = bz + hz + dvec[H_ + j];
  c1n[j] = bn + dvec[2 * H_ + j];
}

// BN over batch per (t,z) + transpose [T,B,Z] -> [B,T,Z]. Grid (16, 8).
__global__ __launch_bounds__(256) void bn_k(const float* __restrict__ outs,
                                            float* __restrict__ y) {
  __shared__ float s_sum[4][64], s_sq[4][64], s_mean[64], s_inv[64];
  const int t = blockIdx.x, zb = blockIdx.y;
  const int zl = threadIdx.x & 63, bp = threadIdx.x >> 6;
  const int z = zb * 64 + zl;
  float sum = 0.f, sq = 0.f;
  for (int b = bp * 64; b < bp * 64 + 64; ++b) {
    float v = outs[(size_t)(t * 256 + b) * Z_ + z];
    sum += v; sq += v * v;
  }
  s_sum[bp][zl] = sum; s_sq[bp][zl] = sq;
  __syncthreads();
  if (bp == 0) {
    float S = s_sum[0][zl] + s_sum[1][zl] + s_sum[2][zl] + s_sum[3][zl];
    float Q = s_sq[0][zl] + s_sq[1][zl] + s_sq[2][zl] + s_sq[3][zl];
    float mean = S * (1.0f / 256.0f);
    float var  = Q * (1.0f / 256.0f) - mean * mean;
    s_mean[zl] = mean;
    s_inv[zl]  = rsqrtf(var + 1e-5f);
  }
  __syncthreads();
  const float mean = s_mean[zl], inv = s_inv[zl];
  for (int b = bp * 64; b < bp * 64 + 64; ++b) {
    float v = outs[(size_t)(t * 256 + b) * Z_ + z];
    y[(size_t)(b * T_ + t) * Z_ + z] = (v - mean) * inv;
  }
}

// ---------------------------------------------------------------------------
extern "C" void kernel_launch(void* const* d_in, const int* in_sizes, int n_in,
                              void* d_out, int out_size, void* d_ws, size_t ws_size,
                              hipStream_t stream) {
  const float* z     = (const float*)d_in[0];
  const float* fc_w  = (const float*)d_in[1];
  const float* fc_b  = (const float*)d_in[2];
  const float* fc_u  = (const float*)d_in[3];
  const float* w_ih  = (const float*)d_in[4];
  const float* w_hh  = (const float*)d_in[5];
  const float* b_ih  = (const float*)d_in[6];
  const float* b_hh  = (const float*)d_in[7];
  const float* lin_w = (const float*)d_in[8];
  const float* lin_b = (const float*)d_in[9];
  float* out = (float*)d_out;

  char* ws = (char*)d_ws;
  size_t off = 0;
  auto alloc = [&](size_t bytes) -> void* {
    off = (off + 255) & ~(size_t)255;
    void* p = ws + off;
    off += bytes;
    return p;
  };
  unsigned short* w_ih_q   = (unsigned short*)alloc((size_t)H3_ * Z_ * 2);
  unsigned short* w_hhn_q  = (unsigned short*)alloc((size_t)H_ * H_ * 2);
  unsigned short* lin_w_q  = (unsigned short*)alloc((size_t)Z_ * H_ * 2);
  unsigned short* lin_wT_q = (unsigned short*)alloc((size_t)Z_ * H_ * 2);
  unsigned short* fc_w_q   = (unsigned short*)alloc((size_t)Z_ * Z_ * 2);
  unsigned short* z_q      = (unsigned short*)alloc((size_t)B_ * Z_ * 2);
  unsigned short* x0_q     = (unsigned short*)alloc((size_t)B_ * Z_ * 2);
  unsigned short* Wsum_r   = (unsigned short*)alloc((size_t)H_ * H_ * 2);
  unsigned short* Wsum_z   = (unsigned short*)alloc((size_t)H_ * H_ * 2);
  unsigned short* Wn_c     = (unsigned short*)alloc((size_t)H_ * H_ * 2);
  unsigned short* Hhist    = (unsigned short*)alloc((size_t)T_ * B_ * H_ * 2);
  float* h_f32 = (float*)alloc((size_t)2 * B_ * H_ * 4);
  float* outs  = (float*)alloc((size_t)T_ * B_ * Z_ * 4);
  float* c0r = (float*)alloc(H_ * 4);
  float* c0z = (float*)alloc(H_ * 4);
  float* c0n = (float*)alloc(H_ * 4);
  float* c1r = (float*)alloc(H_ * 4);
  float* c1z = (float*)alloc(H_ * 4);
  float* c1n = (float*)alloc(H_ * 4);
  float* chn = (float*)alloc(H_ * 4);
  float* dvec = (float*)alloc(H3_ * 4);
  float* t1v = (float*)alloc(Z_ * 4);
  float* t2v = (float*)alloc(Z_ * 4);
  float* invn = (float*)alloc(256);
  float* invsig = (float*)alloc(256);
  (void)in_sizes; (void)n_in; (void)out_size; (void)ws_size;

  quant_all<<<dim3((2195456 + 255) / 256), 256, 0, stream>>>(
      z, fc_w, w_ih, w_hh, lin_w, z_q, fc_w_q, w_ih_q, w_hhn_q, lin_w_q);
  transq<<<dim3(64, 16), 256, 0, stream>>>(lin_w, lin_wT_q);
  sigma1<<<8, 256, 0, stream>>>(fc_w, fc_u, t1v);
  sigma1b<<<1, 256, 0, stream>>>(t1v, invn);
  sigma2<<<128, 256, 0, stream>>>(fc_w, t1v, invn, t2v);
  sigma3<<<1, 256, 0, stream>>>(t2v, invsig);
  dots_k<<<384, 256, 0, stream>>>(w_ih, lin_b, dvec);
  consts_k<<<8, 256, 0, stream>>>(b_ih, b_hh, dvec, c0r, c0z, c0n, c1r, c1z, c1n, chn);

  // x0 = (z @ fc_w^T) * inv_sigma + fc_b   -> bf16
  gemm_bt<<<dim3(B_ / 32, Z_ / 64), 256, 0, stream>>>(
      z_q, fc_w_q, Z_, nullptr, 0, fc_b, invsig, x0_q, nullptr, Z_);

  // W_comb_g = w_ih_g @ lin_w (+ w_hh_g for r,z) -> bf16 [2048][2048]
  for (int g = 0; g < 3; ++g) {
    const float* adds = (g < 2) ? (w_hh + (size_t)g * H_ * H_) : nullptr;
    unsigned short* outw = (g == 0) ? Wsum_r : (g == 1) ? Wsum_z : Wn_c;
    gemm_bt64<<<dim3(H_ / 64, H_ / 64), 256, 0, stream>>>(
        w_ih_q + (size_t)g * H_ * Z_, lin_wT_q, Z_, adds, H_, nullptr,
        outw, nullptr, H_);
  }

  for (int t = 0; t < T_; ++t) {
    if (t == 0) {
      gru_step4<<<256, 512, 0, stream>>>(
          x0_q, Z_,
          w_ih_q, w_ih_q + (size_t)H_ * Z_, w_ih_q + (size_t)2 * H_ * Z_,
          w_ih_q /* dummy, scaled by 0 */,
          c0r, c0z, c0n, chn, 0.0f, nullptr, h_f32, Hhist);
    } else {
      gru_step4<<<256, 512, 0, stream>>>(
          Hhist + (size_t)(t - 1) * B_ * H_, H_,
          Wsum_r, Wsum_z, Wn_c, w_hhn_q,
          c1r, c1z, c1n, chn, 1.0f,
          h_f32 + (size_t)((t - 1) & 1) * B_ * H_,
          h_f32 + (size_t)(t & 1) * B_ * H_,
          Hhist + (size_t)t * B_ * H_);
    }
  }

  // outs[t*256+b][z] = Hhist[t][b] @ lin_w^T + lin_b   (f32)
  gemm_bt64<<<dim3(T_ * B_ / 64, Z_ / 64), 256, 0, stream>>>(
      Hhist, lin_w_q, H_, nullptr, 0, lin_b, nullptr, outs, Z_);

  bn_k<<<dim3(T_, Z_ / 64), 256, 0, stream>>>(outs, out);
}